// Round 8
// baseline (98.064 us; speedup 1.0000x reference)
//
#include <hip/hip_runtime.h>
#include <math.h>

#define BB 4
#define CC 256
#define HH 64
#define WW 64
#define HW 4096
#define XTR 4240   // padded rows per batch: 72 + 4096 + 72
#define XPAD 72

typedef __attribute__((ext_vector_type(8))) _Float16 half8;
typedef __attribute__((ext_vector_type(4))) float f32x4;

__device__ inline void gld16(const void* g, void* l) {
    __builtin_amdgcn_global_load_lds((const __attribute__((address_space(1))) void*)g,
                                     (__attribute__((address_space(3))) void*)l, 16, 0, 0);
}

// ---------------- K1: fused prep: xt (bilinear+transpose), pad rows, W2, W3 ----------
// blocks [0,2048): X_Tp body; [2048,2192): pad rows; [2192,2264): W2; [2264,4568): W3
__global__ __launch_bounds__(256) void prep_kernel(
    const float* __restrict__ tmpl, const float* __restrict__ search,
    const float* __restrict__ ow, const float* __restrict__ mw,
    const float* __restrict__ dw,
    _Float16* __restrict__ XT, _Float16* __restrict__ W2, _Float16* __restrict__ W3) {
    int blk = blockIdx.x;
    int tid = threadIdx.x;
    __shared__ _Float16 ts[64 * 72];

    if (blk < 2048) {
        int ct = blk & 7, y = (blk >> 3) & 63, b = blk >> 9;
        if (ct >= 4) {
            const float* sp = search + ((size_t)(b * CC + (ct - 4) * 64) * HW) + y * 64;
            for (int it = 0; it < 16; ++it) {
                int c_l = it * 4 + (tid >> 6);
                int x = tid & 63;
                ts[c_l * 72 + x] = (_Float16)sp[(size_t)c_l * HW + x];
            }
        } else {
            float sy = 0.5f * (float)y - 0.25f;
            float fy = floorf(sy);
            float wy = sy - fy;
            int y0 = (int)fy;
            int y0c = min(max(y0, 0), 31), y1c = min(max(y0 + 1, 0), 31);
            const float* tp0 = tmpl + ((size_t)(b * CC + ct * 64) * 1024);
            for (int it = 0; it < 16; ++it) {
                int c_l = it * 4 + (tid >> 6);
                int x = tid & 63;
                float sx = 0.5f * (float)x - 0.25f;
                float fx = floorf(sx);
                float wx = sx - fx;
                int x0 = (int)fx;
                int x0c = min(max(x0, 0), 31), x1c = min(max(x0 + 1, 0), 31);
                const float* tp = tp0 + (size_t)c_l * 1024;
                float v00 = tp[y0c * 32 + x0c], v01 = tp[y0c * 32 + x1c];
                float v10 = tp[y1c * 32 + x0c], v11 = tp[y1c * 32 + x1c];
                ts[c_l * 72 + x] = (_Float16)((1.f - wy) * ((1.f - wx) * v00 + wx * v01) +
                                              wy * ((1.f - wx) * v10 + wx * v11));
            }
        }
        __syncthreads();
        size_t rowbase = (size_t)b * XTR + XPAD + (size_t)y * 64;
        for (int it = 0; it < 2; ++it) {
            int idx = it * 256 + tid;
            int x = idx >> 3, w = idx & 7;
            half8 o;
#pragma unroll
            for (int j = 0; j < 8; ++j) o[j] = ts[(w * 8 + j) * 72 + x];
            *(half8*)&XT[(rowbase + x) * 512 + ct * 64 + ((w ^ (x & 7)) * 8)] = o;
        }
    } else if (blk < 2192) {
        int idx = (blk - 2048) * 256 + tid;  // 36864 = 4*144*64
        int w = idx & 63;
        int r = (idx >> 6) % 144;
        int b = idx / 9216;
        int pr = (r < 72) ? r : (r + 4096);
        half8 z = {};
        *(half8*)&XT[((size_t)b * XTR + pr) * 512 + w * 8] = z;
    } else if (blk < 2264) {
        int idx = (blk - 2192) * 256 + tid;  // 18432
        int q = idx & 7;
        int oc = (idx >> 3) & 31;
        int tap = (idx >> 8) % 9;
        int ch = idx / 2304;
        int c0 = ch * 64 + (q ^ (oc & 7)) * 8;
        half8 o;
#pragma unroll
        for (int j = 0; j < 8; ++j) {
            int c = c0 + j;
            float v = 0.f;
            if (oc < 18) v = ow[((size_t)oc * 512 + c) * 9 + tap];
            else if (oc < 27 && tap == 4) v = mw[(size_t)(oc - 18) * 512 + c];
            o[j] = (_Float16)v;
        }
        *(half8*)&W2[(size_t)idx * 8] = o;
    } else {
        int idx = (blk - 2264) * 256 + tid;  // 589824
        int o = idx / 2304;
        int r = idx - o * 2304;
        int k = r >> 8, c = r & 255;
        W3[idx] = (_Float16)dw[(size_t)(o * CC + c) * 9 + k];
    }
}

// ---------------- K4: offset+mask conv as MFMA GEMM over shifted X_Tp ----------------
__global__ __launch_bounds__(256) void offmask_mfma(
    const _Float16* __restrict__ XT, const _Float16* __restrict__ W2,
    const float* __restrict__ ob, const float* __restrict__ mb,
    float* __restrict__ offs, float* __restrict__ maskv) {
    int blk = blockIdx.x;
    int b = blk >> 6, pt = blk & 63;
    int p0 = pt * 64;
    int tid = threadIdx.x, wave = tid >> 6, lane = tid & 63;
    int l15 = lane & 15, kq = lane >> 4;

    __shared__ __align__(16) _Float16 A_s[18432];   // [tap 9][oc 32][64c] 36864 B
    __shared__ __align__(16) _Float16 B_s[12416];   // [194 rows][64c]     24832 B

    f32x4 acc[2];
    acc[0] = (f32x4){0.f, 0.f, 0.f, 0.f};
    acc[1] = (f32x4){0.f, 0.f, 0.f, 0.f};

    const char* xrow = (const char*)(XT + ((size_t)b * XTR + XPAD + p0 - 65) * 512);
    half8 z8 = {};
    int x_ = wave * 16 + l15;

    for (int ch = 0; ch < 8; ++ch) {
        __syncthreads();
        const char* srcA = (const char*)W2 + (size_t)ch * 36864;
#pragma unroll
        for (int it = 0; it < 9; ++it) {
            int b16 = it * 256 + wave * 64;
            gld16(srcA + (size_t)(b16 + lane) * 16, (char*)A_s + b16 * 16);
        }
#pragma unroll
        for (int it = 0; it < 7; ++it) {
            int b16 = it * 256 + wave * 64;
            if (b16 < 1552) {
                int c16 = b16 + lane;
                int r_u = c16 >> 3, q = c16 & 7;
                gld16(xrow + (size_t)r_u * 1024 + ch * 128 + q * 16, (char*)B_s + b16 * 16);
            }
        }
        __syncthreads();

#pragma unroll
        for (int tap = 0; tap < 9; ++tap) {
            int ky = tap / 3 - 1, kx = tap % 3 - 1;
            int dlt = ky * 64 + kx;
            int key = (l15 + dlt + 72) & 7;
            bool iv0 = (kx == -1 && x_ == 0) || (kx == 1 && x_ == 63);
            int r0 = wave * 16 + l15 + 65 + dlt;
#pragma unroll
            for (int ks = 0; ks < 2; ++ks) {
                int qa = ((ks * 4 + kq) ^ (l15 & 7)) * 8;
                int qb = ((ks * 4 + kq) ^ key) * 8;
                half8 fa0 = *(const half8*)&A_s[tap * 2048 + l15 * 64 + qa];
                half8 fa1 = *(const half8*)&A_s[tap * 2048 + (16 + l15) * 64 + qa];
                half8 fb0 = *(const half8*)&B_s[r0 * 64 + qb];
                if (iv0) fb0 = z8;
                acc[0] = __builtin_amdgcn_mfma_f32_16x16x32_f16(fa0, fb0, acc[0], 0, 0, 0);
                acc[1] = __builtin_amdgcn_mfma_f32_16x16x32_f16(fa1, fb0, acc[1], 0, 0, 0);
            }
        }
    }

    int px = p0 + x_;
#pragma unroll
    for (int m = 0; m < 2; ++m) {
#pragma unroll
        for (int r = 0; r < 4; ++r) {
            int oc = m * 16 + kq * 4 + r;
            float v = acc[m][r];
            if (oc < 18) {
                offs[(size_t)(b * 18 + oc) * HW + px] = v + ob[oc];
            } else if (oc < 27) {
                float s = v + mb[oc - 18];
                maskv[(size_t)(b * 9 + oc - 18) * HW + px] = 1.f / (1.f + expf(-s));
            }
        }
    }
}

// ---------------- K6: fused gather + f16 MFMA GEMM (S_T eliminated) ------------------
// out[b][o][p] = sum_kc W3[o][kc] * sample(b,p,kc).  128x64 tile, BK=64.
// B-tile is gathered inline from X_Tp: corner loads issued BEFORE MFMA (T14),
// vmcnt-waited after, interp'd in f32, ds_write'd swizzled (st_16x32).
__global__ __launch_bounds__(256) void deform_mfma(
    const _Float16* __restrict__ XT, const _Float16* __restrict__ W3,
    const float* __restrict__ offs, const float* __restrict__ maskv,
    const float* __restrict__ db, float* __restrict__ out) {
    int blk = blockIdx.x;  // b(4) x ot(2) x pt(64)
    int b = blk >> 7;
    int ot = (blk >> 6) & 1;
    int pt = blk & 63;
    int o0 = ot * 128, p0 = pt * 64;
    int tid = threadIdx.x;
    int wave = tid >> 6, lane = tid & 63;
    int wo = (wave & 1) * 64, wp = (wave >> 1) * 32;

    __shared__ __align__(16) _Float16 As[2][128 * 64];  // 2 x 16 KB
    __shared__ __align__(16) _Float16 Bs[2][64 * 64];   // 2 x 8 KB
    __shared__ ushort4 r4[576];                          // 4.6 KB
    __shared__ float4 wg4[576];                          // 9.2 KB

    // ---- per-block bilinear params for 64 px x 9 taps ----
    for (int i = tid; i < 576; i += 256) {
        int k = i >> 6, t = i & 63;
        int p = p0 + t;
        int y = p >> 6, x = p & 63;
        float dy = offs[((size_t)(b * 18 + 2 * k)) * HW + p];
        float dx = offs[((size_t)(b * 18 + 2 * k + 1)) * HW + p];
        float m = maskv[((size_t)(b * 9 + k)) * HW + p];
        float py = (float)(y + k / 3 - 1) + dy;
        float px = (float)(x + k % 3 - 1) + dx;
        float fy0 = floorf(py), fx0 = floorf(px);
        float wy = py - fy0, wx = px - fx0;
        int y0 = (int)fy0, x0 = (int)fx0;
        bool vy0 = (y0 >= 0) && (y0 < HH);
        bool vy1 = (y0 + 1 >= 0) && (y0 + 1 < HH);
        bool vx0 = (x0 >= 0) && (x0 < WW);
        bool vx1 = (x0 + 1 >= 0) && (x0 + 1 < WW);
        float w00 = (vy0 && vx0) ? (1.f - wy) * (1.f - wx) * m : 0.f;
        float w01 = (vy0 && vx1) ? (1.f - wy) * wx * m : 0.f;
        float w10 = (vy1 && vx0) ? wy * (1.f - wx) * m : 0.f;
        float w11 = (vy1 && vx1) ? wy * wx * m : 0.f;
        int y0c = min(max(y0, 0), HH - 1), y1c = min(max(y0 + 1, 0), HH - 1);
        int x0c = min(max(x0, 0), WW - 1), x1c = min(max(x0 + 1, 0), WW - 1);
        r4[i] = make_ushort4((ushort)(y0c * 64 + x0c), (ushort)(y0c * 64 + x1c),
                             (ushort)(y1c * 64 + x0c), (ushort)(y1c * 64 + x1c));
        wg4[i] = make_float4(w00, w01, w10, w11);
    }

    f32x4 acc[4][2];
#pragma unroll
    for (int i = 0; i < 4; ++i)
#pragma unroll
        for (int j = 0; j < 2; ++j) acc[i][j] = (f32x4){0.f, 0.f, 0.f, 0.f};

    const _Float16* Abase = W3 + (size_t)o0 * 2304;
    const _Float16* xb = XT + ((size_t)b * XTR + XPAD) * 512;
    int fr = lane & 15, kq8 = lane >> 4;
    // per-thread B-gather roles (2 outputs): pixel pl[j], chunk oc8[j]
    const int pl0 = tid >> 3, oc80 = tid & 7;
    const int pl1 = (256 + tid) >> 3, oc81 = tid & 7;

    half8 cr[2][4];   // corner values, live across MFMA
    float4 wgt[2];

    auto stageA = [&](int buf, int ks) {  // 4 gld16 per thread
#pragma unroll
        for (int t = 0; t < 4; ++t) {
            int ci = t * 256 + tid;
            int r = ci >> 3, q = ci & 7;
            gld16(Abase + (size_t)r * 2304 + ks * 64 + ((q ^ (r & 7)) * 8),
                  (char*)&As[buf][0] + (size_t)ci * 16);
        }
    };
    auto issueB = [&](int ks) {  // 8 corner half8 loads to regs
        int k = ks >> 2;
        int gg = (4 + (ks & 3)) * 64;
        ushort4 rr0 = r4[k * 64 + pl0];
        wgt[0] = wg4[k * 64 + pl0];
        cr[0][0] = *(const half8*)(xb + (size_t)rr0.x * 512 + gg + ((oc80 ^ (rr0.x & 7)) * 8));
        cr[0][1] = *(const half8*)(xb + (size_t)rr0.y * 512 + gg + ((oc80 ^ (rr0.y & 7)) * 8));
        cr[0][2] = *(const half8*)(xb + (size_t)rr0.z * 512 + gg + ((oc80 ^ (rr0.z & 7)) * 8));
        cr[0][3] = *(const half8*)(xb + (size_t)rr0.w * 512 + gg + ((oc80 ^ (rr0.w & 7)) * 8));
        ushort4 rr1 = r4[k * 64 + pl1];
        wgt[1] = wg4[k * 64 + pl1];
        cr[1][0] = *(const half8*)(xb + (size_t)rr1.x * 512 + gg + ((oc81 ^ (rr1.x & 7)) * 8));
        cr[1][1] = *(const half8*)(xb + (size_t)rr1.y * 512 + gg + ((oc81 ^ (rr1.y & 7)) * 8));
        cr[1][2] = *(const half8*)(xb + (size_t)rr1.z * 512 + gg + ((oc81 ^ (rr1.z & 7)) * 8));
        cr[1][3] = *(const half8*)(xb + (size_t)rr1.w * 512 + gg + ((oc81 ^ (rr1.w & 7)) * 8));
    };
    auto writeB = [&](int buf) {  // interp in f32, swizzled ds_write
#pragma unroll
        for (int j = 0; j < 2; ++j) {
            half8 o;
#pragma unroll
            for (int e = 0; e < 8; ++e) {
                float v = wgt[j].x * (float)cr[j][0][e] + wgt[j].y * (float)cr[j][1][e] +
                          wgt[j].z * (float)cr[j][2][e] + wgt[j].w * (float)cr[j][3][e];
                o[e] = (_Float16)v;
            }
            int pl_ = j ? pl1 : pl0;
            int oc_ = j ? oc81 : oc80;
            *(half8*)&Bs[buf][pl_ * 64 + ((oc_ ^ (pl_ & 7)) * 8)] = o;
        }
    };

    __syncthreads();  // r4/wg4 ready
    issueB(0);
    stageA(0, 0);
    asm volatile("s_waitcnt vmcnt(0)" ::: "memory");
    writeB(0);
    __syncthreads();

    for (int ks = 0; ks < 36; ++ks) {
        int cur = ks & 1;
        if (ks < 35) {
            issueB(ks + 1);        // corner loads fly under MFMA
            stageA(cur ^ 1, ks + 1);
        }
        __builtin_amdgcn_s_setprio(1);
#pragma unroll
        for (int ks2 = 0; ks2 < 2; ++ks2) {
            int ch = ks2 * 4 + kq8;
            int cho = (ch ^ (fr & 7)) * 8;
            half8 fa[4], fb[2];
#pragma unroll
            for (int f = 0; f < 4; ++f)
                fa[f] = *(const half8*)&As[cur][(wo + f * 16 + fr) * 64 + cho];
#pragma unroll
            for (int g = 0; g < 2; ++g)
                fb[g] = *(const half8*)&Bs[cur][(wp + g * 16 + fr) * 64 + cho];
#pragma unroll
            for (int i = 0; i < 4; ++i)
#pragma unroll
                for (int j = 0; j < 2; ++j)
                    acc[i][j] = __builtin_amdgcn_mfma_f32_16x16x32_f16(fa[i], fb[j], acc[i][j], 0, 0, 0);
        }
        __builtin_amdgcn_s_setprio(0);
        if (ks < 35) {
            asm volatile("s_waitcnt vmcnt(0)" ::: "memory");  // corners + A arrived
            writeB(cur ^ 1);
        }
        __syncthreads();
    }

    int col = lane & 15, rbase = (lane >> 4) * 4;
#pragma unroll
    for (int i = 0; i < 4; ++i) {
        int o_ = o0 + wo + i * 16 + rbase;
#pragma unroll
        for (int j = 0; j < 2; ++j) {
            int p_ = p0 + wp + j * 16 + col;
#pragma unroll
            for (int r = 0; r < 4; ++r) {
                out[((size_t)(b * CC + o_ + r)) * HW + p_] = acc[i][j][r] + db[o_ + r];
            }
        }
    }
}

extern "C" void kernel_launch(void* const* d_in, const int* in_sizes, int n_in,
                              void* d_out, int out_size, void* d_ws, size_t ws_size,
                              hipStream_t stream) {
    const float* tmpl = (const float*)d_in[0];
    const float* search = (const float*)d_in[1];
    const float* ow = (const float*)d_in[2];
    const float* ob = (const float*)d_in[3];
    const float* mw = (const float*)d_in[4];
    const float* mb = (const float*)d_in[5];
    const float* dw = (const float*)d_in[6];
    const float* db = (const float*)d_in[7];
    float* out = (float*)d_out;

    _Float16* XTp = (_Float16*)d_ws;                  // 4*4240*512   = 8,683,520 h
    _Float16* W2 = XTp + (size_t)4 * XTR * 512;       // 147,456 h
    _Float16* W3 = W2 + 147456;                       // 589,824 h
    float* offsv = (float*)(W3 + 589824);             // 294,912 f
    float* maskv = offsv + 294912;                    // 147,456 f
    // total ~20.5 MB

    prep_kernel<<<4568, 256, 0, stream>>>(tmpl, search, ow, mw, dw, XTp, W2, W3);
    offmask_mfma<<<256, 256, 0, stream>>>(XTp, W2, ob, mb, offsv, maskv);
    deform_mfma<<<512, 256, 0, stream>>>(XTp, W3, offsv, maskv, db, out);
}